// Round 1
// baseline (404.157 us; speedup 1.0000x reference)
//
#include <hip/hip_runtime.h>
#include <hip/hip_bf16.h>

// Problem constants (fixed by the reference):
//   N=100000 nodes, E=500000 edges, V=50000, NE=1000000, D=300, C=20, NG=512
#define NG 512
#define D_DIM 300
#define C_DIM 20
#define K3_EPB 2048   // edges per scatter block (8 per thread @ 256 threads)

// ---------------- K1: in-degree + per-graph edge histogram ----------------
__global__ __launch_bounds__(256) void count_kernel(const int* __restrict__ dst,
                                                    const int* __restrict__ graph_ids,
                                                    int* __restrict__ cnt,
                                                    int* __restrict__ gcnt, int E) {
    __shared__ int lg[NG];
    int t = threadIdx.x;
    for (int i = t; i < NG; i += 256) lg[i] = 0;
    __syncthreads();
    for (int e = blockIdx.x * 256 + t; e < E; e += gridDim.x * 256) {
        int d = dst[e];
        atomicAdd(&cnt[d], 1);
        atomicAdd(&lg[graph_ids[d]], 1);
    }
    __syncthreads();
    for (int i = t; i < NG; i += 256)
        if (lg[i]) atomicAdd(&gcnt[i], lg[i]);
}

// ---------------- K2: exclusive scan of 512 bins (single block) ----------------
__global__ __launch_bounds__(NG) void scan_kernel(const int* __restrict__ gcnt,
                                                  int* __restrict__ goff,
                                                  int* __restrict__ gfill) {
    __shared__ int s[NG];
    int t = threadIdx.x;
    int v = gcnt[t];
    s[t] = v;
    __syncthreads();
    for (int off = 1; off < NG; off <<= 1) {
        int x = (t >= off) ? s[t - off] : 0;
        __syncthreads();
        s[t] += x;
        __syncthreads();
    }
    int excl = s[t] - v;
    goff[t] = excl;
    gfill[t] = excl;
}

// ---------------- K3: scatter edges into per-graph contiguous lists ----------------
// Payload per edge: (row = nodes_batch[src[e]], scale = w_e / indeg[dst[e]])
__global__ __launch_bounds__(256) void scatter_kernel(const int* __restrict__ src,
                                                      const int* __restrict__ dst,
                                                      const int* __restrict__ eb,
                                                      const int* __restrict__ nodes_batch,
                                                      const float* __restrict__ edge_embed,
                                                      const int* __restrict__ graph_ids,
                                                      const int* __restrict__ cnt,
                                                      int* __restrict__ gfill,
                                                      int2* __restrict__ elist, int E) {
    __shared__ int bcnt[NG];
    __shared__ int base[NG];
    int t = threadIdx.x;
    int e0 = blockIdx.x * K3_EPB;
    for (int i = t; i < NG; i += 256) bcnt[i] = 0;
    __syncthreads();

    int rows[K3_EPB / 256];
    float scales[K3_EPB / 256];
    int gids[K3_EPB / 256];
#pragma unroll
    for (int k = 0; k < K3_EPB / 256; k++) {
        int e = e0 + k * 256 + t;
        gids[k] = -1;
        if (e < E) {
            int d = dst[e];
            int g = graph_ids[d];
            gids[k] = g;
            rows[k] = nodes_batch[src[e]];
            scales[k] = edge_embed[eb[e]] / (float)max(cnt[d], 1);
            atomicAdd(&bcnt[g], 1);
        }
    }
    __syncthreads();
    // Reserve one contiguous chunk per bin per block (few global atomics).
    for (int i = t; i < NG; i += 256) {
        int c = bcnt[i];
        base[i] = c ? atomicAdd(&gfill[i], c) : 0;
        bcnt[i] = 0;  // reuse as intra-block cursor
    }
    __syncthreads();
#pragma unroll
    for (int k = 0; k < K3_EPB / 256; k++) {
        int g = gids[k];
        if (g >= 0) {
            int pos = base[g] + atomicAdd(&bcnt[g], 1);
            elist[pos] = make_int2(rows[k], __float_as_int(scales[k]));
        }
    }
}

// ---------------- K4: per-graph weighted-row accumulate + fused ReLU-FC ----------------
// One block per graph, 320 threads: thread t (<300) owns output dim t.
__global__ __launch_bounds__(320) void reduce_fc_kernel(const int2* __restrict__ elist,
                                                        const int* __restrict__ goff,
                                                        const int* __restrict__ gcnt,
                                                        const float* __restrict__ node_embed,
                                                        const float* __restrict__ fc_w,
                                                        const float* __restrict__ fc_b,
                                                        float* __restrict__ out) {
    __shared__ float wlds[D_DIM * C_DIM];  // 24 KB
    __shared__ int2 tile[256];
    __shared__ float accs[D_DIM];
    __shared__ float outs[C_DIM];
    int gid = blockIdx.x;
    int t = threadIdx.x;

    for (int i = t; i < D_DIM * C_DIM; i += 320) wlds[i] = fc_w[i];

    int beg = goff[gid];
    int num = gcnt[gid];
    float a = 0.f;
    bool act = t < D_DIM;

    for (int done = 0; done < num; done += 256) {
        int m = min(256, num - done);
        __syncthreads();
        if (t < m) tile[t] = elist[beg + done + t];
        __syncthreads();
#pragma unroll 4
        for (int j = 0; j < m; j++) {
            int2 pr = tile[j];
            float s = __int_as_float(pr.y);
            const float* p = node_embed + (size_t)pr.x * D_DIM;
            if (act) a += s * p[t];
        }
    }
    __syncthreads();
    if (act) accs[t] = a;
    if (t < C_DIM) outs[t] = fc_b[t];
    __syncthreads();
    // FC: 240 threads = 20 cols x 12 chunks of 25 dims
    if (t < C_DIM * 12) {
        int c = t % C_DIM;
        int ch = t / C_DIM;
        float p = 0.f;
#pragma unroll
        for (int d = ch * 25; d < ch * 25 + 25; d++) {
            float gv = accs[d];
            gv = gv > 0.f ? gv : 0.f;
            p += gv * wlds[d * C_DIM + c];
        }
        atomicAdd(&outs[c], p);
    }
    __syncthreads();
    if (t < C_DIM) out[gid * C_DIM + t] = outs[t];
}

// ---------------- Fallback path (small ws): direct atomic scatter ----------------
__global__ __launch_bounds__(256) void fb_count(const int* __restrict__ dst, int* __restrict__ cnt, int E) {
    for (int e = blockIdx.x * 256 + threadIdx.x; e < E; e += gridDim.x * 256)
        atomicAdd(&cnt[dst[e]], 1);
}
__global__ __launch_bounds__(256) void fb_scatter(const int* __restrict__ src, const int* __restrict__ dst,
                                                  const int* __restrict__ eb,
                                                  const int* __restrict__ nodes_batch,
                                                  const float* __restrict__ edge_embed,
                                                  const int* __restrict__ graph_ids,
                                                  const int* __restrict__ cnt,
                                                  const float* __restrict__ ne,
                                                  float* __restrict__ g, int E) {
    int wid = (blockIdx.x * blockDim.x + threadIdx.x) >> 6;
    int lane = threadIdx.x & 63;
    int nw = (gridDim.x * blockDim.x) >> 6;
    for (int e = wid; e < E; e += nw) {
        int d = dst[e];
        int gid = graph_ids[d];
        float s = edge_embed[eb[e]] / (float)max(cnt[d], 1);
        const float* p = ne + (size_t)nodes_batch[src[e]] * D_DIM;
        float* go = g + gid * D_DIM;
        for (int k = lane; k < D_DIM; k += 64) atomicAdd(&go[k], s * p[k]);
    }
}
__global__ __launch_bounds__(256) void fb_fc(const float* __restrict__ g, const float* __restrict__ w,
                                             const float* __restrict__ b, float* __restrict__ out) {
    __shared__ float outs[C_DIM];
    int gid = blockIdx.x, t = threadIdx.x;
    if (t < C_DIM) outs[t] = b[t];
    __syncthreads();
    if (t < C_DIM * 12) {
        int c = t % C_DIM, ch = t / C_DIM;
        float p = 0.f;
        for (int d = ch * 25; d < ch * 25 + 25; d++) {
            float gv = g[gid * D_DIM + d];
            gv = gv > 0.f ? gv : 0.f;
            p += gv * w[d * C_DIM + c];
        }
        atomicAdd(&outs[c], p);
    }
    __syncthreads();
    if (t < C_DIM) out[gid * C_DIM + t] = outs[t];
}

extern "C" void kernel_launch(void* const* d_in, const int* in_sizes, int n_in,
                              void* d_out, int out_size, void* d_ws, size_t ws_size,
                              hipStream_t stream) {
    const int* nodes_batch = (const int*)d_in[0];
    const int* edges_batch = (const int*)d_in[1];
    const int* src = (const int*)d_in[2];
    const int* dst = (const int*)d_in[3];
    const int* graph_ids = (const int*)d_in[4];
    const float* node_embed = (const float*)d_in[5];
    const float* edge_embed = (const float*)d_in[6];
    const float* fc_w = (const float*)d_in[7];
    const float* fc_b = (const float*)d_in[8];
    float* out = (float*)d_out;

    int N = in_sizes[0];
    int E = in_sizes[2];

    char* ws = (char*)d_ws;
    size_t off = 0;
    int* cnt = (int*)(ws + off); off += (size_t)N * 4;
    int* gcnt = (int*)(ws + off); off += NG * 4;
    int* goff = (int*)(ws + off); off += NG * 4;
    int* gfill = (int*)(ws + off); off += NG * 4;
    off = (off + 15) & ~(size_t)15;
    int2* elist = (int2*)(ws + off); off += (size_t)E * 8;

    if (ws_size >= off) {
        hipMemsetAsync(cnt, 0, (size_t)N * 4, stream);
        hipMemsetAsync(gcnt, 0, NG * 4, stream);
        count_kernel<<<128, 256, 0, stream>>>(dst, graph_ids, cnt, gcnt, E);
        scan_kernel<<<1, NG, 0, stream>>>(gcnt, goff, gfill);
        int nsb = (E + K3_EPB - 1) / K3_EPB;
        scatter_kernel<<<nsb, 256, 0, stream>>>(src, dst, edges_batch, nodes_batch, edge_embed,
                                                graph_ids, cnt, gfill, elist, E);
        reduce_fc_kernel<<<NG, 320, 0, stream>>>(elist, goff, gcnt, node_embed, fc_w, fc_b, out);
    } else {
        // Fallback: direct atomic scatter into g (needs only ~1 MB of ws)
        float* g = (float*)(ws + (size_t)N * 4);
        hipMemsetAsync(cnt, 0, (size_t)N * 4, stream);
        hipMemsetAsync(g, 0, (size_t)NG * D_DIM * 4, stream);
        fb_count<<<128, 256, 0, stream>>>(dst, cnt, E);
        fb_scatter<<<512, 256, 0, stream>>>(src, dst, edges_batch, nodes_batch, edge_embed,
                                            graph_ids, cnt, node_embed, g, E);
        fb_fc<<<NG, 256, 0, stream>>>(g, fc_w, fc_b, out);
    }
}

// Round 2
// 243.252 us; speedup vs baseline: 1.6615x; 1.6615x over previous
//
#include <hip/hip_runtime.h>
#include <hip/hip_bf16.h>

// Problem constants (fixed by the reference):
//   N=100000 nodes, E=500000 edges, V=50000, NE=1000000, D=300, C=20, NG=512
#define NG 512
#define D_DIM 300
#define C_DIM 20
#define K3_EPB 2048   // edges per scatter block (8 per thread @ 256 threads)
#define CH 256        // edges per accumulate block

// ---------------- K1: in-degree + per-graph edge histogram ----------------
__global__ __launch_bounds__(256) void count_kernel(const int* __restrict__ dst,
                                                    const int* __restrict__ graph_ids,
                                                    int* __restrict__ cnt,
                                                    int* __restrict__ gcnt, int E) {
    __shared__ int lg[NG];
    int t = threadIdx.x;
    for (int i = t; i < NG; i += 256) lg[i] = 0;
    __syncthreads();
    for (int e = blockIdx.x * 256 + t; e < E; e += gridDim.x * 256) {
        int d = dst[e];
        atomicAdd(&cnt[d], 1);
        atomicAdd(&lg[graph_ids[d]], 1);
    }
    __syncthreads();
    for (int i = t; i < NG; i += 256)
        if (lg[i]) atomicAdd(&gcnt[i], lg[i]);
}

// ---------------- K2: exclusive scan of 512 bins (single block) ----------------
__global__ __launch_bounds__(NG) void scan_kernel(const int* __restrict__ gcnt,
                                                  int* __restrict__ goff,
                                                  int* __restrict__ gfill) {
    __shared__ int s[NG];
    int t = threadIdx.x;
    int v = gcnt[t];
    s[t] = v;
    __syncthreads();
    for (int off = 1; off < NG; off <<= 1) {
        int x = (t >= off) ? s[t - off] : 0;
        __syncthreads();
        s[t] += x;
        __syncthreads();
    }
    int excl = s[t] - v;
    goff[t] = excl;
    gfill[t] = excl;
}

// ---------------- K3: scatter edges into per-graph contiguous lists ----------------
// Payload per edge: (row = nodes_batch[src[e]], scale = w_e / indeg[dst[e]])
__global__ __launch_bounds__(256) void scatter_kernel(const int* __restrict__ src,
                                                      const int* __restrict__ dst,
                                                      const int* __restrict__ eb,
                                                      const int* __restrict__ nodes_batch,
                                                      const float* __restrict__ edge_embed,
                                                      const int* __restrict__ graph_ids,
                                                      const int* __restrict__ cnt,
                                                      int* __restrict__ gfill,
                                                      int2* __restrict__ elist, int E) {
    __shared__ int bcnt[NG];
    __shared__ int base[NG];
    int t = threadIdx.x;
    int e0 = blockIdx.x * K3_EPB;
    for (int i = t; i < NG; i += 256) bcnt[i] = 0;
    __syncthreads();

    int rows[K3_EPB / 256];
    float scales[K3_EPB / 256];
    int gids[K3_EPB / 256];
#pragma unroll
    for (int k = 0; k < K3_EPB / 256; k++) {
        int e = e0 + k * 256 + t;
        gids[k] = -1;
        if (e < E) {
            int d = dst[e];
            int g = graph_ids[d];
            gids[k] = g;
            rows[k] = nodes_batch[src[e]];
            scales[k] = edge_embed[eb[e]] / (float)max(cnt[d], 1);
            atomicAdd(&bcnt[g], 1);
        }
    }
    __syncthreads();
    // Reserve one contiguous chunk per bin per block (few global atomics).
    for (int i = t; i < NG; i += 256) {
        int c = bcnt[i];
        base[i] = c ? atomicAdd(&gfill[i], c) : 0;
        bcnt[i] = 0;  // reuse as intra-block cursor
    }
    __syncthreads();
#pragma unroll
    for (int k = 0; k < K3_EPB / 256; k++) {
        int g = gids[k];
        if (g >= 0) {
            int pos = base[g] + atomicAdd(&bcnt[g], 1);
            elist[pos] = make_int2(rows[k], __float_as_int(scales[k]));
        }
    }
}

// ---------------- K4a: chunked weighted-row accumulate into gacc[NG][300] ----------------
// One block per CH-edge chunk of the graph-sorted elist; register accumulate,
// flush with global atomicAdd only at graph-segment boundaries.
__global__ __launch_bounds__(320) void accum_kernel(const int2* __restrict__ elist,
                                                    const int* __restrict__ goff,
                                                    const float* __restrict__ node_embed,
                                                    float* __restrict__ gacc, int E) {
    __shared__ int2 tile[CH];
    __shared__ int goff_s[NG + 1];
    int t = threadIdx.x;
    int pos0 = blockIdx.x * CH;
    int m = min(CH, E - pos0);

    for (int i = t; i < NG; i += 320) goff_s[i] = goff[i];
    if (t == 0) goff_s[NG] = E;
    if (t < m) tile[t] = elist[pos0 + t];
    __syncthreads();

    // binary search: largest g with goff_s[g] <= pos0  (uniform across block)
    int lo = 0, hi = NG - 1;
    while (lo < hi) {
        int mid = (lo + hi + 1) >> 1;
        if (goff_s[mid] <= pos0) lo = mid; else hi = mid - 1;
    }
    int g = lo;
    bool act = t < D_DIM;

    int j = 0;
    while (j < m) {
        int pos = pos0 + j;
        while (pos >= goff_s[g + 1]) g++;          // skip empty graphs
        int end = min(m, goff_s[g + 1] - pos0);    // segment end within chunk
        float a = 0.f;
#pragma unroll 8
        for (; j < end; j++) {
            int2 pr = tile[j];
            float s = __int_as_float(pr.y);
            if (act) a += s * node_embed[pr.x * D_DIM + t];
        }
        if (act) atomicAdd(&gacc[g * D_DIM + t], a);
    }
}

// ---------------- K4b: per-graph ReLU + FC ----------------
__global__ __launch_bounds__(320) void fc_kernel(const float* __restrict__ gacc,
                                                 const float* __restrict__ fc_w,
                                                 const float* __restrict__ fc_b,
                                                 float* __restrict__ out) {
    __shared__ float wlds[D_DIM * C_DIM];  // 24 KB
    __shared__ float accs[D_DIM];
    __shared__ float outs[C_DIM];
    int gid = blockIdx.x;
    int t = threadIdx.x;
    for (int i = t; i < D_DIM * C_DIM; i += 320) wlds[i] = fc_w[i];
    if (t < D_DIM) accs[t] = gacc[gid * D_DIM + t];
    if (t < C_DIM) outs[t] = fc_b[t];
    __syncthreads();
    // FC: 240 threads = 20 cols x 12 chunks of 25 dims
    if (t < C_DIM * 12) {
        int c = t % C_DIM;
        int ch = t / C_DIM;
        float p = 0.f;
#pragma unroll
        for (int d = ch * 25; d < ch * 25 + 25; d++) {
            float gv = accs[d];
            gv = gv > 0.f ? gv : 0.f;
            p += gv * wlds[d * C_DIM + c];
        }
        atomicAdd(&outs[c], p);
    }
    __syncthreads();
    if (t < C_DIM) out[gid * C_DIM + t] = outs[t];
}

// ---------------- Fallback path (small ws): direct atomic scatter ----------------
__global__ __launch_bounds__(256) void fb_count(const int* __restrict__ dst, int* __restrict__ cnt, int E) {
    for (int e = blockIdx.x * 256 + threadIdx.x; e < E; e += gridDim.x * 256)
        atomicAdd(&cnt[dst[e]], 1);
}
__global__ __launch_bounds__(256) void fb_scatter(const int* __restrict__ src, const int* __restrict__ dst,
                                                  const int* __restrict__ eb,
                                                  const int* __restrict__ nodes_batch,
                                                  const float* __restrict__ edge_embed,
                                                  const int* __restrict__ graph_ids,
                                                  const int* __restrict__ cnt,
                                                  const float* __restrict__ ne,
                                                  float* __restrict__ g, int E) {
    int wid = (blockIdx.x * blockDim.x + threadIdx.x) >> 6;
    int lane = threadIdx.x & 63;
    int nw = (gridDim.x * blockDim.x) >> 6;
    for (int e = wid; e < E; e += nw) {
        int d = dst[e];
        int gid = graph_ids[d];
        float s = edge_embed[eb[e]] / (float)max(cnt[d], 1);
        const float* p = ne + (size_t)nodes_batch[src[e]] * D_DIM;
        float* go = g + gid * D_DIM;
        for (int k = lane; k < D_DIM; k += 64) atomicAdd(&go[k], s * p[k]);
    }
}

extern "C" void kernel_launch(void* const* d_in, const int* in_sizes, int n_in,
                              void* d_out, int out_size, void* d_ws, size_t ws_size,
                              hipStream_t stream) {
    const int* nodes_batch = (const int*)d_in[0];
    const int* edges_batch = (const int*)d_in[1];
    const int* src = (const int*)d_in[2];
    const int* dst = (const int*)d_in[3];
    const int* graph_ids = (const int*)d_in[4];
    const float* node_embed = (const float*)d_in[5];
    const float* edge_embed = (const float*)d_in[6];
    const float* fc_w = (const float*)d_in[7];
    const float* fc_b = (const float*)d_in[8];
    float* out = (float*)d_out;

    int N = in_sizes[0];
    int E = in_sizes[2];

    char* ws = (char*)d_ws;
    size_t off = 0;
    int* cnt = (int*)(ws + off); off += (size_t)N * 4;
    int* gcnt = (int*)(ws + off); off += NG * 4;
    int* goff = (int*)(ws + off); off += NG * 4;
    int* gfill = (int*)(ws + off); off += NG * 4;
    float* gacc = (float*)(ws + off); off += (size_t)NG * D_DIM * 4;
    off = (off + 15) & ~(size_t)15;
    int2* elist = (int2*)(ws + off); off += (size_t)E * 8;

    if (ws_size >= off) {
        hipMemsetAsync(cnt, 0, (size_t)N * 4, stream);
        hipMemsetAsync(gcnt, 0, NG * 4, stream);
        hipMemsetAsync(gacc, 0, (size_t)NG * D_DIM * 4, stream);
        count_kernel<<<256, 256, 0, stream>>>(dst, graph_ids, cnt, gcnt, E);
        scan_kernel<<<1, NG, 0, stream>>>(gcnt, goff, gfill);
        int nsb = (E + K3_EPB - 1) / K3_EPB;
        scatter_kernel<<<nsb, 256, 0, stream>>>(src, dst, edges_batch, nodes_batch, edge_embed,
                                                graph_ids, cnt, gfill, elist, E);
        int nab = (E + CH - 1) / CH;
        accum_kernel<<<nab, 320, 0, stream>>>(elist, goff, node_embed, gacc, E);
        fc_kernel<<<NG, 320, 0, stream>>>(gacc, fc_w, fc_b, out);
    } else {
        // Fallback: direct atomic scatter into g (needs only ~1 MB of ws)
        float* g = (float*)(ws + (size_t)N * 4);
        hipMemsetAsync(cnt, 0, (size_t)N * 4, stream);
        hipMemsetAsync(g, 0, (size_t)NG * D_DIM * 4, stream);
        fb_count<<<128, 256, 0, stream>>>(dst, cnt, E);
        fb_scatter<<<512, 256, 0, stream>>>(src, dst, edges_batch, nodes_batch, edge_embed,
                                            graph_ids, cnt, node_embed, g, E);
        fc_kernel<<<NG, 320, 0, stream>>>(g, fc_w, fc_b, out);
    }
}

// Round 3
// 165.011 us; speedup vs baseline: 2.4493x; 1.4742x over previous
//
#include <hip/hip_runtime.h>
#include <hip/hip_bf16.h>

// Problem constants (fixed by the reference):
//   N=100000 nodes, E=500000 edges, V=50000, NE=1000000, D=300, C=20, NG=512
#define NG 512
#define D_DIM 300
#define C_DIM 20
#define K3_EPB 2048   // edges per scatter block (8 per thread @ 256 threads)
#define CH 256        // edges per accumulate block

// ---------------- K1: in-degree + per-graph edge histogram ----------------
__global__ __launch_bounds__(256) void count_kernel(const int* __restrict__ dst,
                                                    const int* __restrict__ graph_ids,
                                                    int* __restrict__ cnt,
                                                    int* __restrict__ gcnt, int E) {
    __shared__ int lg[NG];
    int t = threadIdx.x;
    for (int i = t; i < NG; i += 256) lg[i] = 0;
    __syncthreads();
    for (int e = blockIdx.x * 256 + t; e < E; e += gridDim.x * 256) {
        int d = dst[e];
        atomicAdd(&cnt[d], 1);
        atomicAdd(&lg[graph_ids[d]], 1);
    }
    __syncthreads();
    for (int i = t; i < NG; i += 256)
        if (lg[i]) atomicAdd(&gcnt[i], lg[i]);
}

// ---------------- K2: exclusive scan of 512 bins (single block) ----------------
__global__ __launch_bounds__(NG) void scan_kernel(const int* __restrict__ gcnt,
                                                  int* __restrict__ goff,
                                                  int* __restrict__ gfill) {
    __shared__ int s[NG];
    int t = threadIdx.x;
    int v = gcnt[t];
    s[t] = v;
    __syncthreads();
    for (int off = 1; off < NG; off <<= 1) {
        int x = (t >= off) ? s[t - off] : 0;
        __syncthreads();
        s[t] += x;
        __syncthreads();
    }
    int excl = s[t] - v;
    goff[t] = excl;
    gfill[t] = excl;
}

// ---------------- K3: scatter edges into per-graph contiguous lists ----------------
// Payload per edge: (row = nodes_batch[src[e]], scale = w_e / indeg[dst[e]])
__global__ __launch_bounds__(256) void scatter_kernel(const int* __restrict__ src,
                                                      const int* __restrict__ dst,
                                                      const int* __restrict__ eb,
                                                      const int* __restrict__ nodes_batch,
                                                      const float* __restrict__ edge_embed,
                                                      const int* __restrict__ graph_ids,
                                                      const int* __restrict__ cnt,
                                                      int* __restrict__ gfill,
                                                      int2* __restrict__ elist, int E) {
    __shared__ int bcnt[NG];
    __shared__ int base[NG];
    int t = threadIdx.x;
    int e0 = blockIdx.x * K3_EPB;
    for (int i = t; i < NG; i += 256) bcnt[i] = 0;
    __syncthreads();

    int rows[K3_EPB / 256];
    float scales[K3_EPB / 256];
    int gids[K3_EPB / 256];
#pragma unroll
    for (int k = 0; k < K3_EPB / 256; k++) {
        int e = e0 + k * 256 + t;
        gids[k] = -1;
        if (e < E) {
            int d = dst[e];
            int g = graph_ids[d];
            gids[k] = g;
            rows[k] = nodes_batch[src[e]];
            scales[k] = edge_embed[eb[e]] / (float)max(cnt[d], 1);
            atomicAdd(&bcnt[g], 1);
        }
    }
    __syncthreads();
    // Reserve one contiguous chunk per bin per block (few global atomics).
    for (int i = t; i < NG; i += 256) {
        int c = bcnt[i];
        base[i] = c ? atomicAdd(&gfill[i], c) : 0;
        bcnt[i] = 0;  // reuse as intra-block cursor
    }
    __syncthreads();
#pragma unroll
    for (int k = 0; k < K3_EPB / 256; k++) {
        int g = gids[k];
        if (g >= 0) {
            int pos = base[g] + atomicAdd(&bcnt[g], 1);
            elist[pos] = make_int2(rows[k], __float_as_int(scales[k]));
        }
    }
}

// ---------------- K4a: chunked weighted-row accumulate into gacc[NG][300] ----------------
// 320 threads = 4 edge-subgroups x 80 lanes; lane owns 4 dims (float4 gather).
// Register accumulate per graph-segment, flush with global atomicAdd.
__global__ __launch_bounds__(320) void accum_kernel(const int2* __restrict__ elist,
                                                    const int* __restrict__ goff,
                                                    const float* __restrict__ node_embed,
                                                    float* __restrict__ gacc, int E) {
    __shared__ int2 tile[CH];
    __shared__ int goff_s[NG + 1];
    int t = threadIdx.x;
    int sub = t / 80;        // 0..3: which edge of each 4-edge wavefront
    int lane = t % 80;       // 0..79: float4 slot within the row
    int d0 = lane * 4;
    bool act = d0 < D_DIM;   // lanes 0..74 active (75*4 = 300)

    int pos0 = blockIdx.x * CH;
    int m = min(CH, E - pos0);

    for (int i = t; i < NG; i += 320) goff_s[i] = goff[i];
    if (t == 0) goff_s[NG] = E;
    for (int i = t; i < m; i += 320) tile[i] = elist[pos0 + i];
    __syncthreads();

    // binary search: largest g with goff_s[g] <= pos0  (uniform across block)
    int lo = 0, hi = NG - 1;
    while (lo < hi) {
        int mid = (lo + hi + 1) >> 1;
        if (goff_s[mid] <= pos0) lo = mid; else hi = mid - 1;
    }
    int g = lo;

    int j = 0;
    while (j < m) {
        while (pos0 + j >= goff_s[g + 1]) g++;     // skip empty graphs
        int end = min(m, goff_s[g + 1] - pos0);    // segment end within chunk
        float ax = 0.f, ay = 0.f, az = 0.f, aw = 0.f;
        if (act) {
#pragma unroll 8
            for (int jj = j + sub; jj < end; jj += 4) {
                int2 pr = tile[jj];
                float s = __int_as_float(pr.y);
                const float4* rowp = (const float4*)(node_embed + (size_t)pr.x * D_DIM);
                float4 v = rowp[lane];
                ax += s * v.x; ay += s * v.y; az += s * v.z; aw += s * v.w;
            }
            float* dest = gacc + g * D_DIM + d0;
            atomicAdd(dest + 0, ax);
            atomicAdd(dest + 1, ay);
            atomicAdd(dest + 2, az);
            atomicAdd(dest + 3, aw);
        }
        j = end;
    }
}

// ---------------- K4b: per-graph ReLU + FC ----------------
__global__ __launch_bounds__(320) void fc_kernel(const float* __restrict__ gacc,
                                                 const float* __restrict__ fc_w,
                                                 const float* __restrict__ fc_b,
                                                 float* __restrict__ out) {
    __shared__ float wlds[D_DIM * C_DIM];  // 24 KB
    __shared__ float accs[D_DIM];
    __shared__ float outs[C_DIM];
    int gid = blockIdx.x;
    int t = threadIdx.x;
    for (int i = t; i < D_DIM * C_DIM; i += 320) wlds[i] = fc_w[i];
    if (t < D_DIM) accs[t] = gacc[gid * D_DIM + t];
    if (t < C_DIM) outs[t] = fc_b[t];
    __syncthreads();
    // FC: 240 threads = 20 cols x 12 chunks of 25 dims
    if (t < C_DIM * 12) {
        int c = t % C_DIM;
        int ch = t / C_DIM;
        float p = 0.f;
#pragma unroll
        for (int d = ch * 25; d < ch * 25 + 25; d++) {
            float gv = accs[d];
            gv = gv > 0.f ? gv : 0.f;
            p += gv * wlds[d * C_DIM + c];
        }
        atomicAdd(&outs[c], p);
    }
    __syncthreads();
    if (t < C_DIM) out[gid * C_DIM + t] = outs[t];
}

// ---------------- Fallback path (small ws): direct atomic scatter ----------------
__global__ __launch_bounds__(256) void fb_count(const int* __restrict__ dst, int* __restrict__ cnt, int E) {
    for (int e = blockIdx.x * 256 + threadIdx.x; e < E; e += gridDim.x * 256)
        atomicAdd(&cnt[dst[e]], 1);
}
__global__ __launch_bounds__(256) void fb_scatter(const int* __restrict__ src, const int* __restrict__ dst,
                                                  const int* __restrict__ eb,
                                                  const int* __restrict__ nodes_batch,
                                                  const float* __restrict__ edge_embed,
                                                  const int* __restrict__ graph_ids,
                                                  const int* __restrict__ cnt,
                                                  const float* __restrict__ ne,
                                                  float* __restrict__ g, int E) {
    int wid = (blockIdx.x * blockDim.x + threadIdx.x) >> 6;
    int lane = threadIdx.x & 63;
    int nw = (gridDim.x * blockDim.x) >> 6;
    for (int e = wid; e < E; e += nw) {
        int d = dst[e];
        int gid = graph_ids[d];
        float s = edge_embed[eb[e]] / (float)max(cnt[d], 1);
        const float* p = ne + (size_t)nodes_batch[src[e]] * D_DIM;
        float* go = g + gid * D_DIM;
        for (int k = lane; k < D_DIM; k += 64) atomicAdd(&go[k], s * p[k]);
    }
}

extern "C" void kernel_launch(void* const* d_in, const int* in_sizes, int n_in,
                              void* d_out, int out_size, void* d_ws, size_t ws_size,
                              hipStream_t stream) {
    const int* nodes_batch = (const int*)d_in[0];
    const int* edges_batch = (const int*)d_in[1];
    const int* src = (const int*)d_in[2];
    const int* dst = (const int*)d_in[3];
    const int* graph_ids = (const int*)d_in[4];
    const float* node_embed = (const float*)d_in[5];
    const float* edge_embed = (const float*)d_in[6];
    const float* fc_w = (const float*)d_in[7];
    const float* fc_b = (const float*)d_in[8];
    float* out = (float*)d_out;

    int N = in_sizes[0];
    int E = in_sizes[2];

    char* ws = (char*)d_ws;
    size_t off = 0;
    int* cnt = (int*)(ws + off); off += (size_t)N * 4;
    int* gcnt = (int*)(ws + off); off += NG * 4;
    int* goff = (int*)(ws + off); off += NG * 4;
    int* gfill = (int*)(ws + off); off += NG * 4;
    float* gacc = (float*)(ws + off); off += (size_t)NG * D_DIM * 4;
    off = (off + 15) & ~(size_t)15;
    int2* elist = (int2*)(ws + off); off += (size_t)E * 8;

    if (ws_size >= off) {
        hipMemsetAsync(cnt, 0, (size_t)N * 4, stream);
        hipMemsetAsync(gcnt, 0, NG * 4, stream);
        hipMemsetAsync(gacc, 0, (size_t)NG * D_DIM * 4, stream);
        count_kernel<<<256, 256, 0, stream>>>(dst, graph_ids, cnt, gcnt, E);
        scan_kernel<<<1, NG, 0, stream>>>(gcnt, goff, gfill);
        int nsb = (E + K3_EPB - 1) / K3_EPB;
        scatter_kernel<<<nsb, 256, 0, stream>>>(src, dst, edges_batch, nodes_batch, edge_embed,
                                                graph_ids, cnt, gfill, elist, E);
        int nab = (E + CH - 1) / CH;
        accum_kernel<<<nab, 320, 0, stream>>>(elist, goff, node_embed, gacc, E);
        fc_kernel<<<NG, 320, 0, stream>>>(gacc, fc_w, fc_b, out);
    } else {
        // Fallback: direct atomic scatter into g (needs only ~1 MB of ws)
        float* g = (float*)(ws + (size_t)N * 4);
        hipMemsetAsync(cnt, 0, (size_t)N * 4, stream);
        hipMemsetAsync(g, 0, (size_t)NG * D_DIM * 4, stream);
        fb_count<<<128, 256, 0, stream>>>(dst, cnt, E);
        fb_scatter<<<512, 256, 0, stream>>>(src, dst, edges_batch, nodes_batch, edge_embed,
                                            graph_ids, cnt, node_embed, g, E);
        fc_kernel<<<NG, 320, 0, stream>>>(g, fc_w, fc_b, out);
    }
}